// Round 17
// baseline (113.925 us; speedup 1.0000x reference)
//
#include <hip/hip_runtime.h>

// B=2, D=64, N=512, H=256, OUT=64
// mid[b] = sum_{c,i} relu( relu(hi[b,i,:]+hcb[b,c,:]) @ w2 + b2 ) @ w3 + N^2*b3
// out = relu(mid @ w4 + b4) @ w5 + b5
//
// big v17: 4 MFMA-issuing waves per SIMD (the untested lever). 256 blocks x
// 1024 threads (16 waves, 1 block/CU, 4/SIMD). Whole B (128 KB, R13 fragment
// order) in LDS; hc from global (L1); A gen'd into 64 regs/tile; per n-block:
// 16 x {ds_read_b128 B + MFMA 32x32x16}, acc = 1 f32x16. Barrier-free main
// loop; VGPR capped at 128 by __launch_bounds__(1024,4).

using f32x16  = __attribute__((ext_vector_type(16))) float;
using short8  = __attribute__((ext_vector_type(8))) short;
using float4v = __attribute__((ext_vector_type(4))) float;

__device__ __forceinline__ short f2bf(float f) {
    unsigned u = __float_as_uint(f);
    unsigned r = u + 0x7FFFu + ((u >> 16) & 1u);   // RNE
    return (short)(r >> 16);
}

__device__ __forceinline__ short8 relu_pack8(float4v lo, float4v hi4) {
#pragma unroll
    for (int e = 0; e < 4; ++e) {
        lo[e]  = fmaxf(lo[e], 0.f);
        hi4[e] = fmaxf(hi4[e], 0.f);
    }
    union { short8 s; unsigned u[4]; } r;
    asm("v_cvt_pk_bf16_f32 %0, %1, %2" : "=v"(r.u[0]) : "v"(lo[0]),  "v"(lo[1]));
    asm("v_cvt_pk_bf16_f32 %0, %1, %2" : "=v"(r.u[1]) : "v"(lo[2]),  "v"(lo[3]));
    asm("v_cvt_pk_bf16_f32 %0, %1, %2" : "=v"(r.u[2]) : "v"(hi4[0]), "v"(hi4[1]));
    asm("v_cvt_pk_bf16_f32 %0, %1, %2" : "=v"(r.u[3]) : "v"(hi4[2]), "v"(hi4[3]));
    return r.s;
}

// ---- prep: blocks [0,256): hi/hcb (4 n-cols per block); [256,512): frag-ordered w2
__global__ __launch_bounds__(256) void prep(const float* __restrict__ in,
                                            const float* __restrict__ w1,
                                            const float* __restrict__ b1,
                                            const float* __restrict__ w2,
                                            float* __restrict__ hi,
                                            float* __restrict__ hcb,
                                            short* __restrict__ bfrag) {
    int tid = threadIdx.x;
    int bidx = blockIdx.x;
    if (bidx < 256) {
        int b = bidx >> 7, n0 = (bidx & 127) * 4;
        __shared__ float xs[4][64];
        {
            int nn = tid >> 6, d = tid & 63;
            xs[nn][d] = in[(size_t)(b * 64 + d) * 512 + n0 + nn];
        }
        __syncthreads();
        float a0[4] = {0.f, 0.f, 0.f, 0.f}, a1[4] = {0.f, 0.f, 0.f, 0.f};
#pragma unroll 8
        for (int d = 0; d < 64; ++d) {
            float wA = w1[d * 256 + tid];
            float wB = w1[(64 + d) * 256 + tid];
#pragma unroll
            for (int nn = 0; nn < 4; ++nn) {
                a0[nn] += xs[nn][d] * wA;
                a1[nn] += xs[nn][d] * wB;
            }
        }
        float bb = b1[tid];
#pragma unroll
        for (int nn = 0; nn < 4; ++nn) {
            size_t o = (size_t)(b * 512 + n0 + nn) * 256 + tid;
            hi[o]  = a0[nn];
            hcb[o] = a1[nn] + bb;
        }
    } else {
        // off = ((n*16+kk)*64 + h*32+col)*8 + j ; value bf16(w2[k][ncol])
        // k = 16kk+8h+j, ncol = n*32+col   (layout correctness-proven in R13)
        int idx = (bidx - 256) * 256 + tid;        // [0, 65536)
        int k = idx >> 8, ncol = idx & 255;
        int n = ncol >> 5, col = ncol & 31;
        int kk = k >> 4, h = (k >> 3) & 1, j = k & 7;
        int off = (((n * 16 + kk) * 64) + h * 32 + col) * 8 + j;
        bfrag[off] = f2bf(w2[k * 256 + ncol]);
    }
}

// ---- big v17: 256 blocks x 1024 threads (16 waves, 4/SIMD), 128 KB LDS
__global__ __launch_bounds__(1024, 4) void big(const float* __restrict__ hi_,
                                               const float* __restrict__ hcb_,
                                               const short8* __restrict__ bfrag,
                                               const float* __restrict__ b2,
                                               float* __restrict__ partials) {
    __shared__ __align__(16) short8 Blds[8192];   // 128 KB: [n 8][kk 16][lane 64]

    const int tid = threadIdx.x;                  // 0..1023
    const int bid = blockIdx.x;                   // [0,256)
    const int b = bid >> 7, cq = bid & 127;

    // stage whole B once (linear, coalesced)
#pragma unroll
    for (int q = 0; q < 8; ++q) Blds[q * 1024 + tid] = bfrag[q * 1024 + tid];
    __syncthreads();                              // the ONLY block-wide barrier

    const int w = tid >> 6, lane = tid & 63;
    const int l31 = lane & 31, h = lane >> 5;
    const int ip = l31 & 7, cq4 = l31 >> 3;

    const float* __restrict__ hib = hi_ + (size_t)b * 131072;
    // hc row for this lane (L1-resident: 4 rows shared block-wide)
    const float* __restrict__ hcl = hcb_ + (size_t)b * 131072
                                  + (size_t)(cq * 4 + cq4) * 256 + h * 8;

    float b2v[8];
#pragma unroll
    for (int n = 0; n < 8; ++n) b2v[n] = b2[n * 32 + l31];
    float jobsum[8] = {0.f, 0.f, 0.f, 0.f, 0.f, 0.f, 0.f, 0.f};

#pragma unroll 1
    for (int t = 0; t < 4; ++t) {
        const int I = w * 4 + t;                  // i-octet [0,64)
        const float* __restrict__ hirow = hib + (size_t)(I * 8 + ip) * 256 + h * 8;

        // ---- gen: one 32-row A tile into 64 fragment regs
        short8 A[16];
#pragma unroll
        for (int kk = 0; kk < 16; ++kk) {
            float4v x0 = *reinterpret_cast<const float4v*>(hirow + kk * 16);
            float4v x1 = *reinterpret_cast<const float4v*>(hirow + kk * 16 + 4);
            float4v c0 = *reinterpret_cast<const float4v*>(hcl + kk * 16);
            float4v c1 = *reinterpret_cast<const float4v*>(hcl + kk * 16 + 4);
            A[kk] = relu_pack8(x0 + c0, x1 + c1);
            if ((kk & 3) == 3) __builtin_amdgcn_sched_barrier(0);   // cap hoisting
        }

        // ---- 8 n-blocks: 16 x {ds_read B + MFMA}; acc = one f32x16
#pragma unroll 1
        for (int n = 0; n < 8; ++n) {
            f32x16 acc;
#pragma unroll
            for (int e = 0; e < 16; ++e) acc = (e == 0) ? acc : acc;  // placeholder
#pragma unroll
            for (int e = 0; e < 16; ++e) acc[e] = b2v[n];
            const short8* __restrict__ bl = Blds + n * 1024 + lane;
            __builtin_amdgcn_s_setprio(1);
#pragma unroll
            for (int kk = 0; kk < 16; ++kk) {
                short8 bf = bl[kk * 64];
                acc = __builtin_amdgcn_mfma_f32_32x32x16_bf16(A[kk], bf, acc, 0, 0, 0);
            }
            __builtin_amdgcn_s_setprio(0);
            float s0 = 0.f, s1 = 0.f;
#pragma unroll
            for (int e = 0; e < 16; e += 2) {
                s0 += fmaxf(acc[e], 0.f);
                s1 += fmaxf(acc[e + 1], 0.f);
            }
            jobsum[n] += s0 + s1;
        }
    }

    // ---- write: combine h halves, one store per (wave, n)
#pragma unroll
    for (int n = 0; n < 8; ++n) {
        jobsum[n] += __shfl_xor(jobsum[n], 32);
        if (h == 0)
            partials[((size_t)(b * 256 + n * 32 + l31)) * 2048 + cq * 16 + w] = jobsum[n];
    }
}

// ---- reduceK: 512 blocks (one per (b,col)) x 256 thr; sums 2048 slots
__global__ __launch_bounds__(256) void reduceK(const float* __restrict__ partials,
                                               float* __restrict__ su_g) {
    int tid = threadIdx.x, blk = blockIdx.x;      // blk = b*256 + col
    const float4v* pv = reinterpret_cast<const float4v*>(partials + (size_t)blk * 2048);
    float4v v0 = pv[tid];
    float4v v1 = pv[tid + 256];
    float s = v0[0] + v0[1] + v0[2] + v0[3] + v1[0] + v1[1] + v1[2] + v1[3];
#pragma unroll
    for (int d = 1; d < 64; d <<= 1) s += __shfl_xor(s, d);
    __shared__ float wsum[4];
    if ((tid & 63) == 0) wsum[tid >> 6] = s;
    __syncthreads();
    if (tid == 0) su_g[blk] = wsum[0] + wsum[1] + wsum[2] + wsum[3];
}

// ---- final tail MLP (reads 512-float su_g), 512 thr
__global__ __launch_bounds__(512) void finalK(const float* __restrict__ su_g,
                                              const float* __restrict__ w3,
                                              const float* __restrict__ b3,
                                              const float* __restrict__ w4,
                                              const float* __restrict__ b4,
                                              const float* __restrict__ w5,
                                              const float* __restrict__ b5,
                                              float* __restrict__ out) {
    __shared__ float su[2][256], mid[2][256], o[2][256];
    int tid = threadIdx.x;
    int b = tid >> 8, c = tid & 255;
    su[b][c] = su_g[b * 256 + c];
    __syncthreads();
    float m = 262144.0f * b3[c];
    for (int k = 0; k < 256; ++k) m += su[b][k] * w3[k * 256 + c];
    mid[b][c] = m;
    __syncthreads();
    float ov = b4[c];
    for (int k = 0; k < 256; ++k) ov += mid[b][k] * w4[k * 256 + c];
    o[b][c] = fmaxf(ov, 0.f);
    __syncthreads();
    if (c < 64) {
        float rr = b5[c];
        for (int k = 0; k < 256; ++k) rr += o[b][k] * w5[k * 64 + c];
        out[b * 64 + c] = rr;
    }
}

extern "C" void kernel_launch(void* const* d_in, const int* in_sizes, int n_in,
                              void* d_out, int out_size, void* d_ws, size_t ws_size,
                              hipStream_t stream) {
    const float* in = (const float*)d_in[0];
    const float* w1 = (const float*)d_in[1];
    const float* b1 = (const float*)d_in[2];
    const float* w2 = (const float*)d_in[3];
    const float* b2 = (const float*)d_in[4];
    const float* w3 = (const float*)d_in[5];
    const float* b3 = (const float*)d_in[6];
    const float* w4 = (const float*)d_in[7];
    const float* b4 = (const float*)d_in[8];
    const float* w5 = (const float*)d_in[9];
    const float* b5 = (const float*)d_in[10];
    float* out = (float*)d_out;

    char* ws = (char*)d_ws;
    float* hi       = (float*)(ws);                                   // 1 MB
    float* hcb      = (float*)(ws + (1u << 20));                      // 1 MB
    short* bfrag    = (short*)(ws + (2u << 20));                      // 128 KB
    float* partials = (float*)(ws + (2u << 20) + (1u << 18));         // 4 MB (2x256x2048)
    float* su_g     = (float*)(ws + (6u << 20) + (1u << 18));         // 2 KB

    prep<<<512, 256, 0, stream>>>(in, w1, b1, w2, hi, hcb, bfrag);
    big<<<256, 1024, 0, stream>>>(hi, hcb, (const short8*)bfrag, b2, partials);
    reduceK<<<512, 256, 0, stream>>>(partials, su_g);
    finalK<<<1, 512, 0, stream>>>(su_g, w3, b3, w4, b4, w5, b5, out);
}